// Round 5
// baseline (2138.768 us; speedup 1.0000x reference)
//
#include <hip/hip_runtime.h>

typedef _Float16 f16;
typedef _Float16 f16x8 __attribute__((ext_vector_type(8)));
typedef float f32x4 __attribute__((ext_vector_type(4)));

// async global->LDS, 16B per lane; LDS dest must be linear (base + lane*16).
__device__ __forceinline__ void gload_lds16(const void* g, void* l) {
  __builtin_amdgcn_global_load_lds(
      (const __attribute__((address_space(1))) void*)g,
      (__attribute__((address_space(3))) void*)l, 16, 0, 0);
}

__device__ __forceinline__ float act_apply(float x, int id) {
  switch (id) {
    case 0: return fmaxf(x, 0.0f);
    case 1: return 1.0f / (1.0f + __expf(-x));
    case 2: return tanhf(x);
    case 3: return x >= 0.0f ? x : 0.1f * x;
    default: return 1.0507009873554805f *
                    (x > 0.0f ? x : 1.6732632423543772f * expm1f(x));
  }
}

// C = act(A @ W^T * Sa + bias) * invSn
// 256x256 tile, 4-slot K32 ring, 8-phase-per-K128 schedule (2 phases/slot):
//   q0: 8 ds_read (A m0-3, B n0-3) + stage A(s+3) + [vmcnt(6) even s] + bar +
//       lgkm0 + 16 MFMA + bar
//   q1: 4 ds_read (A m4-7; B in regs) + stage B(s+3) + bar + lgkm0 + 16 MFMA + bar
// vmcnt never drains below 6 in the main loop (tail via clamped re-stage).
template <bool FINAL>
__global__ __launch_bounds__(512, 2)
void gemm_bias_act(const f16* __restrict__ A, const f16* __restrict__ W,
                   const float* __restrict__ bias, const int* __restrict__ ids,
                   float Sa, float invSn, void* __restrict__ outv,
                   int M, int N, int K) {
  __shared__ f16 lA[4][256 * 32];   // 4 x 16 KiB
  __shared__ f16 lB[4][256 * 32];   // 4 x 16 KiB  (total 128 KiB)

  const int tid  = (int)threadIdx.x;
  const int lane = tid & 63;
  const int wid  = tid >> 6;   // 0..7
  const int wm   = wid >> 2;   // 0..1 : row half (128 rows)
  const int wn   = wid & 3;    // 0..3 : col quarter (64 cols)

  // bijective XCD-aware swizzle (nwg % 8 == 0 for all shapes here)
  const int nbx = N >> 8;
  const int nwg = (M >> 8) * nbx;
  const int b   = (int)blockIdx.x;
  const int swz = (b & 7) * (nwg >> 3) + (b >> 3);
  const int brow = (swz / nbx) << 8;
  const int bcol = (swz % nbx) << 8;

  // ---- staging: pre-swizzled global source, linear LDS dest (0 conflicts, r2/r3) ----
  const int d0 = tid << 4;            // dest byte 0..8191   (rows 0..127)
  const int d1 = d0 + 8192;           // dest byte 8192..16383 (rows 128..255)
  const int s0 = d0 ^ (((d0 >> 7) & 7) << 4);
  const int s1 = d1 ^ (((d1 >> 7) & 7) << 4);
  const int r0 = s0 >> 6, c0 = (s0 >> 4) & 3;   // source row, 16B-block in K
  const int r1 = s1 >> 6, c1 = (s1 >> 4) & 3;

  const f16* pA0 = A + (long)(brow + r0) * K + c0 * 8;
  const f16* pA1 = A + (long)(brow + r1) * K + c1 * 8;
  const f16* pB0 = W + (long)(bcol + r0) * K + c0 * 8;
  const f16* pB1 = W + (long)(bcol + r1) * K + c1 * 8;
  const int e0 = tid << 3;            // LDS dest in elements
  const int e1 = e0 + 4096;

  // ---- fragment read addressing (swizzled, validated r2/r3: 0 conflicts) ----
  const int fr = lane & 15;
  const int kb = lane >> 4;
  const int xorv = ((fr >> 1) & 7) << 4;
  const char* baA = (const char*)&lA[0][0];
  const char* baB = (const char*)&lB[0][0];

  int offA[8], offB[4];
#pragma unroll
  for (int m = 0; m < 8; ++m)
    offA[m] = (((wm * 128 + m * 16 + fr) << 6) + (kb << 4)) ^ xorv;
#pragma unroll
  for (int n = 0; n < 4; ++n)
    offB[n] = (((wn * 64 + n * 16 + fr) << 6) + (kb << 4)) ^ xorv;

  f32x4 acc[8][4];
#pragma unroll
  for (int m = 0; m < 8; ++m)
#pragma unroll
    for (int n = 0; n < 4; ++n) acc[m][n] = (f32x4){0.f, 0.f, 0.f, 0.f};

  const int nt = K >> 5;   // 64 or 128 (>= 4)

  // prologue: slots 0,1,2 staged (A-unit then B-unit each; 12 loads/thread)
#pragma unroll
  for (int t = 0; t < 3; ++t) {
    const long kk = (long)t << 5;
    gload_lds16(pA0 + kk, &lA[t][e0]);
    gload_lds16(pA1 + kk, &lA[t][e1]);
    gload_lds16(pB0 + kk, &lB[t][e0]);
    gload_lds16(pB1 + kk, &lB[t][e1]);
  }
  asm volatile("s_waitcnt vmcnt(8)" ::: "memory");  // slot 0 (A+B) landed
  __builtin_amdgcn_s_barrier();                     // ... for all waves
  asm volatile("" ::: "memory");

  for (int s = 0; s < nt; ++s) {
    const int so  = (s & 3) << 14;                 // current slot byte offset
    const int ps  = (s + 3 < nt) ? (s + 3) : (nt - 1);  // clamped stage tile
    const int pso = ps & 3;                        // its ring slot
    const long kk = (long)ps << 5;

    f16x8 af[4], bf[4];

    // ================= phase q0 : A m0-3 x B n0-3 =================
#pragma unroll
    for (int m = 0; m < 4; ++m) af[m] = *(const f16x8*)(baA + so + offA[m]);
#pragma unroll
    for (int n = 0; n < 4; ++n) bf[n] = *(const f16x8*)(baB + so + offB[n]);
    gload_lds16(pA0 + kk, &lA[pso][e0]);           // stage A-unit(s+3)
    gload_lds16(pA1 + kk, &lA[pso][e1]);
    if (!(s & 1)) asm volatile("s_waitcnt vmcnt(6)" ::: "memory");
    __builtin_amdgcn_s_barrier();
    asm volatile("s_waitcnt lgkmcnt(0)" ::: "memory");
    __builtin_amdgcn_sched_barrier(0);
    __builtin_amdgcn_s_setprio(1);
#pragma unroll
    for (int m = 0; m < 4; ++m)
#pragma unroll
      for (int n = 0; n < 4; ++n)
        acc[m][n] = __builtin_amdgcn_mfma_f32_16x16x32_f16(af[m], bf[n],
                                                           acc[m][n], 0, 0, 0);
    __builtin_amdgcn_s_setprio(0);
    __builtin_amdgcn_sched_barrier(0);
    __builtin_amdgcn_s_barrier();

    // ================= phase q1 : A m4-7 x B n0-3 (B in regs) =================
#pragma unroll
    for (int m = 0; m < 4; ++m) af[m] = *(const f16x8*)(baA + so + offA[m + 4]);
    gload_lds16(pB0 + kk, &lB[pso][e0]);           // stage B-unit(s+3)
    gload_lds16(pB1 + kk, &lB[pso][e1]);
    __builtin_amdgcn_s_barrier();
    asm volatile("s_waitcnt lgkmcnt(0)" ::: "memory");
    __builtin_amdgcn_sched_barrier(0);
    __builtin_amdgcn_s_setprio(1);
#pragma unroll
    for (int m = 0; m < 4; ++m)
#pragma unroll
      for (int n = 0; n < 4; ++n)
        acc[4 + m][n] = __builtin_amdgcn_mfma_f32_16x16x32_f16(af[m], bf[n],
                                                               acc[4 + m][n],
                                                               0, 0, 0);
    __builtin_amdgcn_s_setprio(0);
    __builtin_amdgcn_sched_barrier(0);
    __builtin_amdgcn_s_barrier();
  }
  asm volatile("s_waitcnt vmcnt(0)" ::: "memory");  // drain clamped re-stages

  // D layout: row = (lane>>4)*4 + reg, col = lane&15  (m89-verified)
  const int r4 = (lane >> 4) << 2;
#pragma unroll
  for (int n = 0; n < 4; ++n) {
    const int gcol = bcol + wn * 64 + n * 16 + fr;
    const float bv = bias[gcol];
    const int id   = ids[gcol];
#pragma unroll
    for (int m = 0; m < 8; ++m) {
      const int grow = brow + wm * 128 + m * 16 + r4;
#pragma unroll
      for (int i = 0; i < 4; ++i) {
        const float y = act_apply(acc[m][n][i] * Sa + bv, id);
        if (FINAL) {
          ((float*)outv)[(long)(grow + i) * N + gcol] = y;
        } else {
          ((f16*)outv)[(long)(grow + i) * N + gcol] = (f16)(y * invSn);
        }
      }
    }
  }
}

__global__ void cvt_f32_to_f16(const float* __restrict__ in, f16* __restrict__ out,
                               float scale, int n) {
  int i = ((int)blockIdx.x * 256 + (int)threadIdx.x) * 8;
  const int stride = (int)gridDim.x * 256 * 8;
  for (; i < n; i += stride) {
    const float4 v0 = *(const float4*)(in + i);
    const float4 v1 = *(const float4*)(in + i + 4);
    f16x8 h;
    h[0] = (f16)(v0.x * scale); h[1] = (f16)(v0.y * scale);
    h[2] = (f16)(v0.z * scale); h[3] = (f16)(v0.w * scale);
    h[4] = (f16)(v1.x * scale); h[5] = (f16)(v1.y * scale);
    h[6] = (f16)(v1.z * scale); h[7] = (f16)(v1.w * scale);
    *(f16x8*)(out + i) = h;
  }
}

extern "C" void kernel_launch(void* const* d_in, const int* in_sizes, int n_in,
                              void* d_out, int out_size, void* d_ws, size_t ws_size,
                              hipStream_t stream) {
  (void)in_sizes; (void)n_in; (void)out_size; (void)ws_size;
  const int M = 8192, IND = 2048, HID = 4096, OUTD = 2048;
  const float* x = (const float*)d_in[0];

  // workspace: actA (8192*4096 f16) | actB (8192*4096 f16) | wbuf (4096*4096 f16)
  f16* actA = (f16*)d_ws;
  f16* actB = actA + (size_t)M * HID;
  f16* wbuf = actB + (size_t)M * HID;

  // static per-layer activation scales (powers of 2, exact): h_i stored as h/S[i]
  const float S[6] = {1.f, 16.f, 512.f, 16384.f, 262144.f, 8388608.f};

  const int Ks[6] = {IND, HID, HID, HID, HID, HID};
  const int Ns[6] = {HID, HID, HID, HID, HID, OUTD};

  cvt_f32_to_f16<<<2048, 256, 0, stream>>>(x, actA, 1.0f, M * IND);

  f16* cur = actA;
  f16* nxt = actB;
  for (int i = 0; i < 6; ++i) {
    const int K = Ks[i], N = Ns[i];
    const float* w  = (const float*)d_in[1 + 3 * i];
    const float* bs = (const float*)d_in[2 + 3 * i];
    const int* id   = (const int*)d_in[3 + 3 * i];

    cvt_f32_to_f16<<<2048, 256, 0, stream>>>(w, wbuf, 1.0f, N * K);

    const int nblk = (M >> 8) * (N >> 8);
    if (i < 5) {
      gemm_bias_act<false><<<nblk, 512, 0, stream>>>(
          cur, wbuf, bs, id, S[i], 1.0f / S[i + 1], nxt, M, N, K);
      f16* t = cur; cur = nxt; nxt = t;
    } else {
      gemm_bias_act<true><<<nblk, 512, 0, stream>>>(
          cur, wbuf, bs, id, S[i], 1.0f, d_out, M, N, K);
    }
  }
}

// Round 6
// 1942.572 us; speedup vs baseline: 1.1010x; 1.1010x over previous
//
#include <hip/hip_runtime.h>

typedef _Float16 f16;
typedef _Float16 f16x8 __attribute__((ext_vector_type(8)));
typedef float f32x4 __attribute__((ext_vector_type(4)));

// async global->LDS, 16B per lane; LDS dest must be linear (base + lane*16).
__device__ __forceinline__ void gload_lds16(const void* g, void* l) {
  __builtin_amdgcn_global_load_lds(
      (const __attribute__((address_space(1))) void*)g,
      (__attribute__((address_space(3))) void*)l, 16, 0, 0);
}

__device__ __forceinline__ float act_apply(float x, int id) {
  switch (id) {
    case 0: return fmaxf(x, 0.0f);
    case 1: return 1.0f / (1.0f + __expf(-x));
    case 2: return tanhf(x);
    case 3: return x >= 0.0f ? x : 0.1f * x;
    default: return 1.0507009873554805f *
                    (x > 0.0f ? x : 1.6732632423543772f * expm1f(x));
  }
}

// ============================================================================
// Variant A: 256x256 tile, 4-slot K32 ring, ONE barrier + one vmcnt(4) per
// slot, no lgkm fences — compiler overlaps ds_read with MFMA (read-ahead regs).
// ============================================================================
template <bool FINAL>
__global__ __launch_bounds__(512, 2)
void gemm256(const f16* __restrict__ A, const f16* __restrict__ W,
             const float* __restrict__ bias, const int* __restrict__ ids,
             float Sa, float invSn, void* __restrict__ outv,
             int M, int N, int K) {
  __shared__ f16 lA[4][256 * 32];   // 4 x 16 KiB
  __shared__ f16 lB[4][256 * 32];   // 4 x 16 KiB

  const int tid  = (int)threadIdx.x;
  const int lane = tid & 63;
  const int wid  = tid >> 6;
  const int wm   = wid >> 2;   // 0..1
  const int wn   = wid & 3;    // 0..3

  const int nbx = N >> 8;
  const int nwg = (M >> 8) * nbx;
  const int b   = (int)blockIdx.x;
  const int swz = (b & 7) * (nwg >> 3) + (b >> 3);
  const int brow = (swz / nbx) << 8;
  const int bcol = (swz % nbx) << 8;

  // staging: pre-swizzled global source, linear LDS dest (0 conflicts, r2-r5)
  const int d0 = tid << 4;
  const int d1 = d0 + 8192;
  const int s0 = d0 ^ (((d0 >> 7) & 7) << 4);
  const int s1 = d1 ^ (((d1 >> 7) & 7) << 4);
  const int r0 = s0 >> 6, c0 = (s0 >> 4) & 3;
  const int r1 = s1 >> 6, c1 = (s1 >> 4) & 3;

  const f16* pA0 = A + (long)(brow + r0) * K + c0 * 8;
  const f16* pA1 = A + (long)(brow + r1) * K + c1 * 8;
  const f16* pB0 = W + (long)(bcol + r0) * K + c0 * 8;
  const f16* pB1 = W + (long)(bcol + r1) * K + c1 * 8;
  const int e0 = tid << 3;
  const int e1 = e0 + 4096;

  const int fr = lane & 15;
  const int kb = lane >> 4;
  const int xorv = ((fr >> 1) & 7) << 4;
  const char* baA = (const char*)&lA[0][0];
  const char* baB = (const char*)&lB[0][0];

  int offA[8], offB[4];
#pragma unroll
  for (int m = 0; m < 8; ++m)
    offA[m] = (((wm * 128 + m * 16 + fr) << 6) + (kb << 4)) ^ xorv;
#pragma unroll
  for (int n = 0; n < 4; ++n)
    offB[n] = (((wn * 64 + n * 16 + fr) << 6) + (kb << 4)) ^ xorv;

  f32x4 acc[8][4];
#pragma unroll
  for (int m = 0; m < 8; ++m)
#pragma unroll
    for (int n = 0; n < 4; ++n) acc[m][n] = (f32x4){0.f, 0.f, 0.f, 0.f};

  const int nt = K >> 5;   // 64 or 128 (even, >= 4)

  // prologue: stage tiles 0,1,2
#pragma unroll
  for (int t = 0; t < 3; ++t) {
    const long kk = (long)t << 5;
    gload_lds16(pA0 + kk, &lA[t][e0]);
    gload_lds16(pA1 + kk, &lA[t][e1]);
    gload_lds16(pB0 + kk, &lB[t][e0]);
    gload_lds16(pB1 + kk, &lB[t][e1]);
  }
  asm volatile("s_waitcnt vmcnt(4)" ::: "memory");  // tiles 0,1 landed
  __builtin_amdgcn_s_barrier();                     // ... for all waves
  asm volatile("" ::: "memory");

  f16x8 aC[4], bC[4], aN[4], bN[4], aL[4];
#pragma unroll
  for (int m = 0; m < 4; ++m) aC[m] = *(const f16x8*)(baA + offA[m]);
#pragma unroll
  for (int n = 0; n < 4; ++n) bC[n] = *(const f16x8*)(baB + offB[n]);

  // body u: reads slot u's late-A + slot u+1's (A0-3,B) frags; stages tile
  // u+3 (clamped); 32 MFMA on regs; gate = vmcnt(4)+barrier (tile u+2 landed).
#define BODY(U, AC, BC, AN, BN)                                            \
  do {                                                                     \
    const int so  = ((U) & 3) << 14;                                       \
    const int son = (((U) + 1) & 3) << 14;                                 \
    _Pragma("unroll")                                                      \
    for (int m = 0; m < 4; ++m)                                            \
      aL[m] = *(const f16x8*)(baA + so + offA[m + 4]);                     \
    if ((U) + 1 < nt) {                                                    \
      _Pragma("unroll")                                                    \
      for (int m = 0; m < 4; ++m)                                          \
        AN[m] = *(const f16x8*)(baA + son + offA[m]);                      \
      _Pragma("unroll")                                                    \
      for (int n = 0; n < 4; ++n)                                          \
        BN[n] = *(const f16x8*)(baB + son + offB[n]);                      \
    }                                                                      \
    {                                                                      \
      const int ps  = ((U) + 3 < nt) ? (U) + 3 : nt - 1;                   \
      const int pso = ps & 3;                                              \
      const long kk = (long)ps << 5;                                       \
      gload_lds16(pA0 + kk, &lA[pso][e0]);                                 \
      gload_lds16(pA1 + kk, &lA[pso][e1]);                                 \
      gload_lds16(pB0 + kk, &lB[pso][e0]);                                 \
      gload_lds16(pB1 + kk, &lB[pso][e1]);                                 \
    }                                                                      \
    __builtin_amdgcn_s_setprio(1);                                         \
    _Pragma("unroll")                                                      \
    for (int m = 0; m < 4; ++m)                                            \
      _Pragma("unroll")                                                    \
      for (int n = 0; n < 4; ++n)                                          \
        acc[m][n] = __builtin_amdgcn_mfma_f32_16x16x32_f16(                \
            AC[m], BC[n], acc[m][n], 0, 0, 0);                             \
    _Pragma("unroll")                                                      \
    for (int m = 0; m < 4; ++m)                                            \
      _Pragma("unroll")                                                    \
      for (int n = 0; n < 4; ++n)                                          \
        acc[4 + m][n] = __builtin_amdgcn_mfma_f32_16x16x32_f16(            \
            aL[m], BC[n], acc[4 + m][n], 0, 0, 0);                         \
    __builtin_amdgcn_s_setprio(0);                                         \
    if ((U) < nt - 1) {                                                    \
      asm volatile("s_waitcnt vmcnt(4)" ::: "memory");                     \
      __builtin_amdgcn_s_barrier();                                        \
      asm volatile("" ::: "memory");                                       \
    }                                                                      \
  } while (0)

  for (int s = 0; s < nt; s += 2) {
    BODY(s, aC, bC, aN, bN);
    BODY(s + 1, aN, bN, aC, bC);
  }
#undef BODY
  asm volatile("s_waitcnt vmcnt(0)" ::: "memory");  // drain clamped re-stages

  const int r4 = (lane >> 4) << 2;
#pragma unroll
  for (int n = 0; n < 4; ++n) {
    const int gcol = bcol + wn * 64 + n * 16 + fr;
    const float bv = bias[gcol];
    const int id   = ids[gcol];
#pragma unroll
    for (int m = 0; m < 8; ++m) {
      const int grow = brow + wm * 128 + m * 16 + r4;
#pragma unroll
      for (int i = 0; i < 4; ++i) {
        const float y = act_apply(acc[m][n][i] * Sa + bv, id);
        if (FINAL) {
          ((float*)outv)[(long)(grow + i) * N + gcol] = y;
        } else {
          ((f16*)outv)[(long)(grow + i) * N + gcol] = (f16)(y * invSn);
        }
      }
    }
  }
}

// ============================================================================
// Variant B: m97-clone. 128x128 tile, BK=32, 2-deep dbuf, __syncthreads
// drain, 4 blocks/CU (implicit cross-block overlap), swizzled LDS.
// ============================================================================
template <bool FINAL>
__global__ __launch_bounds__(256, 4)
void gemm128(const f16* __restrict__ A, const f16* __restrict__ W,
             const float* __restrict__ bias, const int* __restrict__ ids,
             float Sa, float invSn, void* __restrict__ outv,
             int M, int N, int K) {
  __shared__ f16 lA[2][128 * 32];   // 2 x 8 KiB
  __shared__ f16 lB[2][128 * 32];   // 2 x 8 KiB  (total 32 KiB)

  const int tid  = (int)threadIdx.x;
  const int lane = tid & 63;
  const int wid  = tid >> 6;   // 0..3
  const int wr   = (wid >> 1) * 64;
  const int wc   = (wid & 1) * 64;

  const int nbx = N >> 7;
  const int nwg = (M >> 7) * nbx;
  const int b   = (int)blockIdx.x;
  const int swz = (b & 7) * (nwg >> 3) + (b >> 3);
  const int brow = (swz / nbx) << 7;
  const int bcol = (swz % nbx) << 7;

  // staging: pre-swizzled source, linear dest; region 8 KiB per matrix
  const int d0 = tid << 4;            // 0..4095
  const int d1 = d0 + 4096;           // 4096..8191
  const int s0 = d0 ^ (((d0 >> 7) & 7) << 4);
  const int s1 = d1 ^ (((d1 >> 7) & 7) << 4);
  const int r0 = s0 >> 6, c0 = (s0 >> 4) & 3;
  const int r1 = s1 >> 6, c1 = (s1 >> 4) & 3;

  const f16* pA0 = A + (long)(brow + r0) * K + c0 * 8;
  const f16* pA1 = A + (long)(brow + r1) * K + c1 * 8;
  const f16* pB0 = W + (long)(bcol + r0) * K + c0 * 8;
  const f16* pB1 = W + (long)(bcol + r1) * K + c1 * 8;
  const int e0 = tid << 3;
  const int e1 = e0 + 2048;

  const int fr = lane & 15;
  const int kb = lane >> 4;
  const int xorv = ((fr >> 1) & 7) << 4;

  int offA[4], offB[4];
#pragma unroll
  for (int m = 0; m < 4; ++m)
    offA[m] = (((wr + m * 16 + fr) << 6) + (kb << 4)) ^ xorv;
#pragma unroll
  for (int n = 0; n < 4; ++n)
    offB[n] = (((wc + n * 16 + fr) << 6) + (kb << 4)) ^ xorv;

  f32x4 acc[4][4];
#pragma unroll
  for (int m = 0; m < 4; ++m)
#pragma unroll
    for (int n = 0; n < 4; ++n) acc[m][n] = (f32x4){0.f, 0.f, 0.f, 0.f};

  const int nt = K >> 5;
  int buf = 0;

  gload_lds16(pA0, &lA[0][e0]);
  gload_lds16(pA1, &lA[0][e1]);
  gload_lds16(pB0, &lB[0][e0]);
  gload_lds16(pB1, &lB[0][e1]);
  __syncthreads();   // compiler drains vmcnt before s_barrier

  for (int t = 0; t < nt; ++t) {
    if (t + 1 < nt) {
      const long kk = (long)(t + 1) << 5;
      gload_lds16(pA0 + kk, &lA[buf ^ 1][e0]);
      gload_lds16(pA1 + kk, &lA[buf ^ 1][e1]);
      gload_lds16(pB0 + kk, &lB[buf ^ 1][e0]);
      gload_lds16(pB1 + kk, &lB[buf ^ 1][e1]);
    }
    const char* bA = (const char*)&lA[buf][0];
    const char* bB = (const char*)&lB[buf][0];
    f16x8 af[4], bf[4];
#pragma unroll
    for (int m = 0; m < 4; ++m) af[m] = *(const f16x8*)(bA + offA[m]);
#pragma unroll
    for (int n = 0; n < 4; ++n) bf[n] = *(const f16x8*)(bB + offB[n]);
#pragma unroll
    for (int m = 0; m < 4; ++m)
#pragma unroll
      for (int n = 0; n < 4; ++n)
        acc[m][n] = __builtin_amdgcn_mfma_f32_16x16x32_f16(af[m], bf[n],
                                                           acc[m][n], 0, 0, 0);
    if (t + 1 < nt) {
      __syncthreads();
      buf ^= 1;
    }
  }

  const int r4 = (lane >> 4) << 2;
#pragma unroll
  for (int n = 0; n < 4; ++n) {
    const int gcol = bcol + wc + n * 16 + fr;
    const float bv = bias[gcol];
    const int id   = ids[gcol];
#pragma unroll
    for (int m = 0; m < 4; ++m) {
      const int grow = brow + wr + m * 16 + r4;
#pragma unroll
      for (int i = 0; i < 4; ++i) {
        const float y = act_apply(acc[m][n][i] * Sa + bv, id);
        if (FINAL) {
          ((float*)outv)[(long)(grow + i) * N + gcol] = y;
        } else {
          ((f16*)outv)[(long)(grow + i) * N + gcol] = (f16)(y * invSn);
        }
      }
    }
  }
}

__global__ void cvt_f32_to_f16(const float* __restrict__ in, f16* __restrict__ out,
                               float scale, int n) {
  int i = ((int)blockIdx.x * 256 + (int)threadIdx.x) * 8;
  const int stride = (int)gridDim.x * 256 * 8;
  for (; i < n; i += stride) {
    const float4 v0 = *(const float4*)(in + i);
    const float4 v1 = *(const float4*)(in + i + 4);
    f16x8 h;
    h[0] = (f16)(v0.x * scale); h[1] = (f16)(v0.y * scale);
    h[2] = (f16)(v0.z * scale); h[3] = (f16)(v0.w * scale);
    h[4] = (f16)(v1.x * scale); h[5] = (f16)(v1.y * scale);
    h[6] = (f16)(v1.z * scale); h[7] = (f16)(v1.w * scale);
    *(f16x8*)(out + i) = h;
  }
}

extern "C" void kernel_launch(void* const* d_in, const int* in_sizes, int n_in,
                              void* d_out, int out_size, void* d_ws, size_t ws_size,
                              hipStream_t stream) {
  (void)in_sizes; (void)n_in; (void)out_size; (void)ws_size;
  const int M = 8192, IND = 2048, HID = 4096, OUTD = 2048;
  const float* x = (const float*)d_in[0];

  f16* actA = (f16*)d_ws;
  f16* actB = actA + (size_t)M * HID;
  f16* wbuf = actB + (size_t)M * HID;

  // static per-layer activation scales (powers of 2, exact)
  const float S[6] = {1.f, 16.f, 512.f, 16384.f, 262144.f, 8388608.f};
  const int Ks[6] = {IND, HID, HID, HID, HID, HID};
  const int Ns[6] = {HID, HID, HID, HID, HID, OUTD};

  cvt_f32_to_f16<<<2048, 256, 0, stream>>>(x, actA, 1.0f, M * IND);

  f16* cur = actA;
  f16* nxt = actB;
  for (int i = 0; i < 6; ++i) {
    const int K = Ks[i], N = Ns[i];
    const float* w  = (const float*)d_in[1 + 3 * i];
    const float* bs = (const float*)d_in[2 + 3 * i];
    const int* id   = (const int*)d_in[3 + 3 * i];

    cvt_f32_to_f16<<<2048, 256, 0, stream>>>(w, wbuf, 1.0f, N * K);

    // A/B fork: layers 0-2 -> gemm256 (1-barrier ring), layers 3-5 -> gemm128
    // (m97-clone, 4 blocks/CU). Layers 1,2 vs 3,4 are identical shapes.
    if (i < 3) {
      const int nblk = (M >> 8) * (N >> 8);
      gemm256<false><<<nblk, 512, 0, stream>>>(
          cur, wbuf, bs, id, S[i], 1.0f / S[i + 1], nxt, M, N, K);
      f16* t = cur; cur = nxt; nxt = t;
    } else if (i < 5) {
      const int nblk = (M >> 7) * (N >> 7);
      gemm128<false><<<nblk, 256, 0, stream>>>(
          cur, wbuf, bs, id, S[i], 1.0f / S[i + 1], nxt, M, N, K);
      f16* t = cur; cur = nxt; nxt = t;
    } else {
      const int nblk = (M >> 7) * (N >> 7);
      gemm128<true><<<nblk, 256, 0, stream>>>(
          cur, wbuf, bs, id, S[i], 1.0f, d_out, M, N, K);
    }
  }
}